// Round 1
// baseline (494.975 us; speedup 1.0000x reference)
//
#include <hip/hip_runtime.h>
#include <math.h>

#define EPSF 1.1920928955078125e-07f

constexpr int N_ = 8, C_ = 8, F_ = 257, T_ = 1500, A_ = 512;
constexpr int NF = N_ * F_;          // 2056
constexpr int CS = F_ * T_;          // channel stride in x (385500)

// ---- ws layout (float offsets) ----
constexpr size_t OFF_MAX  = 0;                       // 2056
constexpr size_t OFF_SUM  = 2056;                    // 2056
constexpr size_t OFF_MT   = 4352;                    // N*F*T = 3084000
constexpr size_t OFF_RS   = (OFF_MT + (size_t)N_*F_*T_ + 63) & ~(size_t)63; // NF*64*2
constexpr size_t OFF_RN   = OFF_RS + (size_t)NF*64*2;
constexpr size_t OFF_FEAT = OFF_RN + (size_t)NF*64*2;   // N*C*F
constexpr size_t OFF_G    = OFF_FEAT + (size_t)N_*C_*F_; // 64
constexpr size_t OFF_WC   = OFF_G + 64;                  // NF*8*2

__global__ void zero_kernel(float* __restrict__ p, int n) {
  int i = blockIdx.x * 256 + threadIdx.x;
  if (i < n) p[i] = 0.f;
}

// per (n,f): max_t |m|, sum_t m   (atomics over T-chunks)
__global__ void mask_stats(const float* __restrict__ m, float* __restrict__ maxabs,
                           float* __restrict__ summ) {
  int f = blockIdx.x * 256 + threadIdx.x;
  int n = blockIdx.z;
  if (f >= F_) return;
  int t0 = blockIdx.y * 100, t1 = min(t0 + 100, T_);
  float mx = 0.f, sm = 0.f;
  for (int t = t0; t < t1; ++t) {
    float v = m[((size_t)n * T_ + t) * F_ + f];
    mx = fmaxf(mx, fabsf(v));
    sm += v;
  }
  atomicMax((unsigned int*)(maxabs + n * F_ + f), __float_as_uint(mx));
  atomicAdd(summ + n * F_ + f, sm);
}

// m[n][t][f] -> mt[n][f][t]  (raw, un-normalized)
__global__ void mask_transpose(const float* __restrict__ m, float* __restrict__ mt) {
  __shared__ float tile[32][33];
  int n = blockIdx.z;
  int f0 = blockIdx.x * 32, t0 = blockIdx.y * 32;
  int tx = threadIdx.x, ty = threadIdx.y;  // 32 x 8
  #pragma unroll
  for (int r = 0; r < 4; ++r) {
    int t = t0 + ty + r * 8, f = f0 + tx;
    if (t < T_ && f < F_) tile[ty + r * 8][tx] = m[((size_t)n * T_ + t) * F_ + f];
  }
  __syncthreads();
  #pragma unroll
  for (int r = 0; r < 4; ++r) {
    int f = f0 + ty + r * 8, t = t0 + tx;
    if (t < T_ && f < F_) mt[((size_t)n * F_ + f) * T_ + t] = tile[tx][ty + r * 8];
  }
}

// one wave per (n,f): accumulate full and m-weighted outer products, finalize Rs / Rn_reg
__global__ __launch_bounds__(64) void covar_kernel(
    const float* __restrict__ xr, const float* __restrict__ xi,
    const float* __restrict__ mt, const float* __restrict__ maxabs,
    const float* __restrict__ summ, float* __restrict__ Rs, float* __restrict__ Rn) {
  int item = blockIdx.x;           // n*F + f
  int lane = threadIdx.x;
  int n = item / F_, f = item % F_;
  size_t base = (size_t)(n * C_) * CS + (size_t)f * T_;
  const float* mrow = mt + (size_t)item * T_;

  float fr[36], fi[36], wr[36], wi[36];
  #pragma unroll
  for (int p = 0; p < 36; ++p) { fr[p] = 0.f; fi[p] = 0.f; wr[p] = 0.f; wi[p] = 0.f; }

  for (int t = lane; t < T_; t += 64) {
    float mv = mrow[t];
    float re[8], im[8];
    #pragma unroll
    for (int c = 0; c < 8; ++c) {
      re[c] = xr[base + (size_t)c * CS + t];
      im[c] = xi[base + (size_t)c * CS + t];
    }
    int p = 0;
    #pragma unroll
    for (int c = 0; c < 8; ++c) {
      #pragma unroll
      for (int d = 0; d <= c; ++d) {
        float pre = re[c] * re[d] + im[c] * im[d];
        fr[p] += pre;
        wr[p] += mv * pre;
        if (d != c) {
          float pim = im[c] * re[d] - re[c] * im[d];
          fi[p] += pim;
          wi[p] += mv * pim;
        }
        ++p;
      }
    }
  }

  // butterfly reduce across the wave (diag fi/wi are constant 0 -> folded)
  #pragma unroll
  for (int p = 0; p < 36; ++p) {
    #pragma unroll
    for (int s = 1; s < 64; s <<= 1) {
      fr[p] += __shfl_xor(fr[p], s);
      fi[p] += __shfl_xor(fi[p], s);
      wr[p] += __shfl_xor(wr[p], s);
      wi[p] += __shfl_xor(wi[p], s);
    }
  }

  __shared__ float s_fr[36], s_fi[36], s_wr[36], s_wi[36];
  if (lane == 0) {
    #pragma unroll
    for (int p = 0; p < 36; ++p) { s_fr[p] = fr[p]; s_fi[p] = fi[p]; s_wr[p] = wr[p]; s_wi[p] = wi[p]; }
  }
  __syncthreads();

  float inv  = 1.f / (maxabs[item] + EPSF);
  float msum = summ[item] * inv;
  float dens = fmaxf(msum, EPSF);
  float denn = fmaxf((float)T_ - msum, EPSF);

  int c = lane >> 3, d = lane & 7;
  int cc = max(c, d), dd = min(c, d);
  int p = cc * (cc + 1) / 2 + dd;
  float sgn = (d > c) ? -1.f : 1.f;

  float nsr = s_wr[p] * inv, nsi = sgn * s_wi[p] * inv;     // masked (speech) numerator
  float flr = s_fr[p],       fli = sgn * s_fi[p];           // full sum
  float rs_re = nsr / dens, rs_im = nsi / dens;
  float rn_re = (flr - nsr) / denn, rn_im = (fli - nsi) / denn;
  if (c == d) rn_re += EPSF;  // Rn_reg = Rn + eps*I

  ((float2*)Rs)[(size_t)item * 64 + lane] = make_float2(rs_re, rs_im);
  ((float2*)Rn)[(size_t)item * 64 + lane] = make_float2(rn_re, rn_im);
}

// feat[n][c][f] = |sum_{d!=c} Rs[n,f,c,d]| / 7
__global__ void feat_kernel(const float* __restrict__ Rs, float* __restrict__ feat) {
  int item = blockIdx.x * 256 + threadIdx.x;
  if (item >= NF) return;
  int n = item / F_, f = item % F_;
  const float2* R = (const float2*)Rs + (size_t)item * 64;
  #pragma unroll
  for (int c = 0; c < 8; ++c) {
    float sre = 0.f, sim = 0.f;
    #pragma unroll
    for (int d = 0; d < 8; ++d) {
      if (d != c) { float2 v = R[c * 8 + d]; sre += v.x; sim += v.y; }
    }
    sre /= 7.f; sim /= 7.f;
    feat[((size_t)(n * C_ + c)) * F_ + f] = sqrtf(sre * sre + sim * sim);
  }
}

// g[n*8+c] = sum_a tanh(feat.proj_w[a] + proj_b[a]) * gvec_w[a] + gvec_b
__global__ __launch_bounds__(256) void proj_kernel(
    const float* __restrict__ feat, const float* __restrict__ pw,
    const float* __restrict__ pb, const float* __restrict__ gw,
    const float* __restrict__ gb, float* __restrict__ g) {
  __shared__ float sfeat[F_];
  __shared__ float red[256];
  int nc = blockIdx.x;
  for (int i = threadIdx.x; i < F_; i += 256) sfeat[i] = feat[(size_t)nc * F_ + i];
  __syncthreads();
  float acc = 0.f;
  for (int a = threadIdx.x; a < A_; a += 256) {
    const float* wrow = pw + (size_t)a * F_;
    float s = 0.f;
    #pragma unroll 4
    for (int ff = 0; ff < F_; ++ff) s += sfeat[ff] * wrow[ff];
    acc += tanhf(s + pb[a]) * gw[a];
  }
  red[threadIdx.x] = acc;
  __syncthreads();
  for (int s = 128; s; s >>= 1) {
    if (threadIdx.x < (unsigned)s) red[threadIdx.x] += red[threadIdx.x + s];
    __syncthreads();
  }
  if (threadIdx.x == 0) g[nc] = red[0] + gb[0];
}

// 8 lanes per (n,f): Gauss-Jordan inverse of Rn_reg, then w = Rn_inv (Rs u) / tr(Rn_inv Rs); store conj(w)
__global__ __launch_bounds__(64) void mvdr_kernel(
    const float* __restrict__ Rs, const float* __restrict__ Rn,
    const float* __restrict__ g, float* __restrict__ wc) {
  int lane = threadIdx.x;
  int item = blockIdx.x * 8 + (lane >> 3);
  int r = lane & 7;
  int base = lane & ~7;
  int n = item / F_;

  const float2* RnM = (const float2*)Rn + (size_t)item * 64;
  const float2* RsM = (const float2*)Rs + (size_t)item * 64;
  float ar[8], ai[8], br[8], bi[8], rsr[8], rsi[8];
  #pragma unroll
  for (int j = 0; j < 8; ++j) {
    float2 v = RnM[r * 8 + j]; ar[j] = v.x; ai[j] = v.y;
    float2 w = RsM[r * 8 + j]; rsr[j] = w.x; rsi[j] = w.y;
    br[j] = (j == r) ? 1.f : 0.f; bi[j] = 0.f;
  }

  #pragma unroll
  for (int k = 0; k < 8; ++k) {
    if (r == k) {  // normalize pivot row
      float dre = ar[k], dim = ai[k];
      float s = 1.f / (dre * dre + dim * dim);
      float cre = dre * s, cim = -dim * s;
      #pragma unroll
      for (int j = 0; j < 8; ++j) {
        float t0 = ar[j] * cre - ai[j] * cim, t1 = ar[j] * cim + ai[j] * cre;
        ar[j] = t0; ai[j] = t1;
        float u0 = br[j] * cre - bi[j] * cim, u1 = br[j] * cim + bi[j] * cre;
        br[j] = u0; bi[j] = u1;
      }
    }
    float par[8], pai[8], pbr[8], pbi[8];
    #pragma unroll
    for (int j = 0; j < 8; ++j) {
      par[j] = __shfl(ar[j], base + k); pai[j] = __shfl(ai[j], base + k);
      pbr[j] = __shfl(br[j], base + k); pbi[j] = __shfl(bi[j], base + k);
    }
    if (r != k) {  // eliminate
      float fre = ar[k], fim = ai[k];
      #pragma unroll
      for (int j = 0; j < 8; ++j) {
        ar[j] -= fre * par[j] - fim * pai[j];
        ai[j] -= fre * pai[j] + fim * par[j];
        br[j] -= fre * pbr[j] - fim * pbi[j];
        bi[j] -= fre * pbi[j] + fim * pbr[j];
      }
    }
  }

  // softmax u over channels
  float gv[8];
  #pragma unroll
  for (int d = 0; d < 8; ++d) gv[d] = g[n * 8 + d];
  float gm = gv[0];
  #pragma unroll
  for (int d = 1; d < 8; ++d) gm = fmaxf(gm, gv[d]);
  float u[8], usum = 0.f;
  #pragma unroll
  for (int d = 0; d < 8; ++d) { u[d] = expf(gv[d] - gm); usum += u[d]; }
  float uinv = 1.f / usum;
  #pragma unroll
  for (int d = 0; d < 8; ++d) u[d] *= uinv;

  // a[r] = (Rs u)[r]
  float avr = 0.f, avi = 0.f;
  #pragma unroll
  for (int d = 0; d < 8; ++d) { avr += rsr[d] * u[d]; avi += rsi[d] * u[d]; }

  // wnum[r] = sum_d Binv[r][d] * a[d]
  float wnr = 0.f, wni = 0.f;
  #pragma unroll
  for (int d = 0; d < 8; ++d) {
    float adr = __shfl(avr, base + d), adi = __shfl(avi, base + d);
    wnr += br[d] * adr - bi[d] * adi;
    wni += br[d] * adi + bi[d] * adr;
  }

  // trace part: sum_d Binv[r][d] * conj(Rs[r][d])  (Rs Hermitian)
  float trr = 0.f, tri = 0.f;
  #pragma unroll
  for (int d = 0; d < 8; ++d) {
    trr += br[d] * rsr[d] + bi[d] * rsi[d];
    tri += bi[d] * rsr[d] - br[d] * rsi[d];
  }
  #pragma unroll
  for (int s = 1; s < 8; s <<= 1) { trr += __shfl_xor(trr, s); tri += __shfl_xor(tri, s); }
  trr += EPSF;

  float den = trr * trr + tri * tri;
  float wre = (wnr * trr + wni * tri) / den;
  float wim = (wni * trr - wnr * tri) / den;
  ((float2*)wc)[(size_t)item * 8 + r] = make_float2(wre, -wim);  // conj(w)
}

// beam[n,f,t] = sum_c conj(w) x ; output (N,T,F,2) via LDS transpose
__global__ __launch_bounds__(256) void beamform_kernel(
    const float* __restrict__ xr, const float* __restrict__ xi,
    const float* __restrict__ wc, float* __restrict__ out) {
  __shared__ float lds[64][33];
  int fb = blockIdx.x * 16, tb = blockIdx.y * 64, n = blockIdx.z;
  int j = threadIdx.x & 63, i0 = threadIdx.x >> 6;
  int t = tb + j;
  bool tok = t < T_;
  float accr[4], acci[4];
  #pragma unroll
  for (int q = 0; q < 4; ++q) { accr[q] = 0.f; acci[q] = 0.f; }

  #pragma unroll
  for (int q = 0; q < 4; ++q) {
    int f = fb + i0 + q * 4;
    if (f < F_ && tok) {
      size_t boff = ((size_t)(n * C_) * F_ + f) * T_ + t;
      const float2* wrow = (const float2*)wc + ((size_t)n * F_ + f) * 8;
      #pragma unroll
      for (int c = 0; c < 8; ++c) {
        float2 w = wrow[c];
        float xre = xr[boff + (size_t)c * CS];
        float xim = xi[boff + (size_t)c * CS];
        accr[q] += w.x * xre - w.y * xim;
        acci[q] += w.x * xim + w.y * xre;
      }
    }
  }
  #pragma unroll
  for (int q = 0; q < 4; ++q) {
    int i = i0 + q * 4;
    lds[j][i * 2]     = accr[q];
    lds[j][i * 2 + 1] = acci[q];
  }
  __syncthreads();

  int idx = threadIdx.x & 31;     // f_loc*2 + comp
  int tr0 = threadIdx.x >> 5;     // 0..7
  #pragma unroll
  for (int pass = 0; pass < 8; ++pass) {
    int tl = pass * 8 + tr0;
    int tt = tb + tl;
    int fl = idx >> 1, comp = idx & 1;
    int ff = fb + fl;
    if (tt < T_ && ff < F_)
      out[(((size_t)n * T_ + tt) * F_ + ff) * 2 + comp] = lds[tl][idx];
  }
}

extern "C" void kernel_launch(void* const* d_in, const int* in_sizes, int n_in,
                              void* d_out, int out_size, void* d_ws, size_t ws_size,
                              hipStream_t stream) {
  const float* m  = (const float*)d_in[0];
  const float* xr = (const float*)d_in[1];
  const float* xi = (const float*)d_in[2];
  const float* pw = (const float*)d_in[3];
  const float* pb = (const float*)d_in[4];
  const float* gw = (const float*)d_in[5];
  const float* gb = (const float*)d_in[6];
  float* ws  = (float*)d_ws;
  float* out = (float*)d_out;

  float* maxabs = ws + OFF_MAX;
  float* summ   = ws + OFF_SUM;
  float* mt     = ws + OFF_MT;
  float* Rs     = ws + OFF_RS;
  float* Rn     = ws + OFF_RN;
  float* feat   = ws + OFF_FEAT;
  float* g      = ws + OFF_G;
  float* wc     = ws + OFF_WC;

  hipLaunchKernelGGL(zero_kernel, dim3(17), dim3(256), 0, stream, maxabs, 4112);
  hipLaunchKernelGGL(mask_stats, dim3(2, 15, 8), dim3(256), 0, stream, m, maxabs, summ);
  hipLaunchKernelGGL(mask_transpose, dim3(9, 47, 8), dim3(32, 8), 0, stream, m, mt);
  hipLaunchKernelGGL(covar_kernel, dim3(NF), dim3(64), 0, stream, xr, xi, mt, maxabs, summ, Rs, Rn);
  hipLaunchKernelGGL(feat_kernel, dim3((NF + 255) / 256), dim3(256), 0, stream, Rs, feat);
  hipLaunchKernelGGL(proj_kernel, dim3(64), dim3(256), 0, stream, feat, pw, pb, gw, gb, g);
  hipLaunchKernelGGL(mvdr_kernel, dim3(NF / 8), dim3(64), 0, stream, Rs, Rn, g, wc);
  hipLaunchKernelGGL(beamform_kernel, dim3(17, 24, 8), dim3(256), 0, stream, xr, xi, wc, out);
}

// Round 3
// 466.450 us; speedup vs baseline: 1.0612x; 1.0612x over previous
//
#include <hip/hip_runtime.h>
#include <math.h>

#define EPSF 1.1920928955078125e-07f

constexpr int N_ = 8, C_ = 8, F_ = 257, T_ = 1500, A_ = 512;
constexpr int NF = N_ * F_;          // 2056
constexpr int CS = F_ * T_;          // channel stride in x (385500)
constexpr int CS4 = CS / 4;          // 96375
constexpr int T4 = T_ / 4;           // 375

// ---- ws layout (float offsets) ----
constexpr size_t OFF_MAX  = 0;                       // 2056
constexpr size_t OFF_SUM  = 2056;                    // 2056
constexpr size_t OFF_MT   = 4352;                    // N*F*T = 3084000
constexpr size_t OFF_RS   = (OFF_MT + (size_t)N_*F_*T_ + 63) & ~(size_t)63; // NF*64*2
constexpr size_t OFF_RN   = OFF_RS + (size_t)NF*64*2;
constexpr size_t OFF_FEAT = OFF_RN + (size_t)NF*64*2;   // N*C*F
constexpr size_t OFF_G    = OFF_FEAT + (size_t)N_*C_*F_; // 64
constexpr size_t OFF_WC   = OFF_G + 64;                  // NF*8*2

__device__ __forceinline__ float get4(const float4& v, int k) {
  switch (k) { case 0: return v.x; case 1: return v.y; case 2: return v.z; default: return v.w; }
}

// fused transpose + per-(n,f) stats: m[n][t][f] -> mt[n][f][t], maxabs, summ (atomics)
__global__ void mask_prep(const float* __restrict__ m, float* __restrict__ mt,
                          float* __restrict__ maxabs, float* __restrict__ summ) {
  __shared__ float tile[32][33];
  int n = blockIdx.z;
  int f0 = blockIdx.x * 32, t0 = blockIdx.y * 32;
  int tx = threadIdx.x, ty = threadIdx.y;  // 32 x 8
  #pragma unroll
  for (int r = 0; r < 4; ++r) {
    int t = t0 + ty + r * 8, f = f0 + tx;
    tile[ty + r * 8][tx] = (t < T_ && f < F_) ? m[((size_t)n * T_ + t) * F_ + f] : 0.f;
  }
  __syncthreads();
  #pragma unroll
  for (int r = 0; r < 4; ++r) {
    int f = f0 + ty + r * 8, t = t0 + tx;
    float v = tile[tx][ty + r * 8];
    if (t < T_ && f < F_) mt[((size_t)n * F_ + f) * T_ + t] = v;
    // reduce over tx (32 lanes; m >= 0 so max-with-0 padding is safe)
    float lm = v, ls = v;
    #pragma unroll
    for (int s = 1; s < 32; s <<= 1) {
      lm = fmaxf(lm, __shfl_xor(lm, s));
      ls += __shfl_xor(ls, s);
    }
    if (tx == 0 && f < F_) {
      atomicMax((unsigned int*)(maxabs + n * F_ + f), __float_as_uint(lm));
      atomicAdd(summ + n * F_ + f, ls);
    }
  }
}

// one wave per (n,f): float4 streaming accumulation of full & m-weighted outer products;
// finalize Rs / Rn_reg and the channel-attention feature row.
__global__ __launch_bounds__(64, 2) void covar_kernel(
    const float* __restrict__ xr, const float* __restrict__ xi,
    const float* __restrict__ mt, const float* __restrict__ maxabs,
    const float* __restrict__ summ, float* __restrict__ Rs, float* __restrict__ Rn,
    float* __restrict__ feat) {
  int item = blockIdx.x;           // n*F + f
  int lane = threadIdx.x;
  int n = item / F_, f = item % F_;
  size_t b4 = (((size_t)(n * C_) * CS) + (size_t)f * T_) >> 2;  // float4 units
  const float4* pxr = (const float4*)xr;
  const float4* pxi = (const float4*)xi;
  const float4* m4  = (const float4*)(mt + (size_t)item * T_);

  float fr[36], wr[36], fi[28], wi[28];
  #pragma unroll
  for (int p = 0; p < 36; ++p) { fr[p] = 0.f; wr[p] = 0.f; }
  #pragma unroll
  for (int p = 0; p < 28; ++p) { fi[p] = 0.f; wi[p] = 0.f; }

  #pragma unroll
  for (int pass = 0; pass < 6; ++pass) {
    int tq = pass * 64 + lane;     // float4 index within the T row
    if (tq < T4) {
      float4 mv = m4[tq];
      float4 ar[8], ai[8];
      #pragma unroll
      for (int c = 0; c < 8; ++c) {
        ar[c] = pxr[b4 + (size_t)c * CS4 + tq];
        ai[c] = pxi[b4 + (size_t)c * CS4 + tq];
      }
      #pragma unroll
      for (int k = 0; k < 4; ++k) {
        float mvk = get4(mv, k);
        float re[8], im[8];
        #pragma unroll
        for (int c = 0; c < 8; ++c) { re[c] = get4(ar[c], k); im[c] = get4(ai[c], k); }
        int p = 0, q = 0;
        #pragma unroll
        for (int c = 0; c < 8; ++c) {
          #pragma unroll
          for (int d = 0; d <= c; ++d) {
            float pre = re[c] * re[d] + im[c] * im[d];
            fr[p] += pre;
            wr[p] = fmaf(mvk, pre, wr[p]);
            if (d != c) {
              float pim = im[c] * re[d] - re[c] * im[d];
              fi[q] += pim;
              wi[q] = fmaf(mvk, pim, wi[q]);
              ++q;
            }
            ++p;
          }
        }
      }
    }
  }

  // butterfly reduce across the wave
  #pragma unroll
  for (int s = 1; s < 64; s <<= 1) {
    #pragma unroll
    for (int p = 0; p < 36; ++p) { fr[p] += __shfl_xor(fr[p], s); wr[p] += __shfl_xor(wr[p], s); }
    #pragma unroll
    for (int p = 0; p < 28; ++p) { fi[p] += __shfl_xor(fi[p], s); wi[p] += __shfl_xor(wi[p], s); }
  }

  __shared__ float s_fr[36], s_wr[36], s_fi[28], s_wi[28];
  if (lane == 0) {
    #pragma unroll
    for (int p = 0; p < 36; ++p) { s_fr[p] = fr[p]; s_wr[p] = wr[p]; }
    #pragma unroll
    for (int p = 0; p < 28; ++p) { s_fi[p] = fi[p]; s_wi[p] = wi[p]; }
  }
  __syncthreads();

  float inv  = 1.f / (maxabs[item] + EPSF);
  float msum = summ[item] * inv;
  float dens = fmaxf(msum, EPSF);
  float denn = fmaxf((float)T_ - msum, EPSF);

  int c = lane >> 3, d = lane & 7;
  int cc = max(c, d), dd = min(c, d);
  int p = cc * (cc + 1) / 2 + dd;
  bool offd = (c != d);
  float sgn = (d > c) ? -1.f : 1.f;
  float swr = s_wr[p], sfr = s_fr[p], swi = 0.f, sfi = 0.f;
  if (offd) {
    int q = cc * (cc - 1) / 2 + dd;
    swi = sgn * s_wi[q];
    sfi = sgn * s_fi[q];
  }
  float nsr = swr * inv, nsi = swi * inv;          // masked (speech) numerator
  float rs_re = nsr / dens, rs_im = nsi / dens;
  float rn_re = (sfr - nsr) / denn, rn_im = (sfi - nsi) / denn;
  if (!offd) rn_re += EPSF;                        // Rn_reg = Rn + eps*I

  ((float2*)Rs)[(size_t)item * 64 + lane] = make_float2(rs_re, rs_im);
  ((float2*)Rn)[(size_t)item * 64 + lane] = make_float2(rn_re, rn_im);

  // feat[n][c][f] = |sum_{d!=c} Rs[c][d]| / 7  (reduce over d within 8-lane groups)
  float offr = offd ? rs_re : 0.f, offi = offd ? rs_im : 0.f;
  #pragma unroll
  for (int s = 1; s < 8; s <<= 1) { offr += __shfl_xor(offr, s); offi += __shfl_xor(offi, s); }
  if (d == 0)
    feat[((size_t)(n * C_ + c)) * F_ + f] = sqrtf(offr * offr + offi * offi) * (1.f / 7.f);
}

// g[n*8+c] = sum_a tanh(feat.proj_w[a] + proj_b[a]) * gvec_w[a] + gvec_b
__global__ __launch_bounds__(256) void proj_kernel(
    const float* __restrict__ feat, const float* __restrict__ pw,
    const float* __restrict__ pb, const float* __restrict__ gw,
    const float* __restrict__ gb, float* __restrict__ g) {
  __shared__ float sfeat[F_];
  __shared__ float red[256];
  int nc = blockIdx.x;
  for (int i = threadIdx.x; i < F_; i += 256) sfeat[i] = feat[(size_t)nc * F_ + i];
  __syncthreads();
  float acc = 0.f;
  for (int a = threadIdx.x; a < A_; a += 256) {
    const float* wrow = pw + (size_t)a * F_;
    float s = 0.f;
    #pragma unroll 4
    for (int ff = 0; ff < F_; ++ff) s += sfeat[ff] * wrow[ff];
    acc += tanhf(s + pb[a]) * gw[a];
  }
  red[threadIdx.x] = acc;
  __syncthreads();
  for (int s = 128; s; s >>= 1) {
    if (threadIdx.x < (unsigned)s) red[threadIdx.x] += red[threadIdx.x + s];
    __syncthreads();
  }
  if (threadIdx.x == 0) g[nc] = red[0] + gb[0];
}

// 8 lanes per (n,f): Gauss-Jordan inverse of Rn_reg, then w = Rn_inv (Rs u) / tr(Rn_inv Rs); store conj(w)
__global__ __launch_bounds__(64) void mvdr_kernel(
    const float* __restrict__ Rs, const float* __restrict__ Rn,
    const float* __restrict__ g, float* __restrict__ wc) {
  int lane = threadIdx.x;
  int item = blockIdx.x * 8 + (lane >> 3);
  int r = lane & 7;
  int base = lane & ~7;
  int n = item / F_;

  const float2* RnM = (const float2*)Rn + (size_t)item * 64;
  const float2* RsM = (const float2*)Rs + (size_t)item * 64;
  float ar[8], ai[8], br[8], bi[8], rsr[8], rsi[8];
  #pragma unroll
  for (int j = 0; j < 8; ++j) {
    float2 v = RnM[r * 8 + j]; ar[j] = v.x; ai[j] = v.y;
    float2 w = RsM[r * 8 + j]; rsr[j] = w.x; rsi[j] = w.y;
    br[j] = (j == r) ? 1.f : 0.f; bi[j] = 0.f;
  }

  #pragma unroll
  for (int k = 0; k < 8; ++k) {
    if (r == k) {
      float dre = ar[k], dim = ai[k];
      float s = 1.f / (dre * dre + dim * dim);
      float cre = dre * s, cim = -dim * s;
      #pragma unroll
      for (int j = 0; j < 8; ++j) {
        float t0 = ar[j] * cre - ai[j] * cim, t1 = ar[j] * cim + ai[j] * cre;
        ar[j] = t0; ai[j] = t1;
        float u0 = br[j] * cre - bi[j] * cim, u1 = br[j] * cim + bi[j] * cre;
        br[j] = u0; bi[j] = u1;
      }
    }
    float par[8], pai[8], pbr[8], pbi[8];
    #pragma unroll
    for (int j = 0; j < 8; ++j) {
      par[j] = __shfl(ar[j], base + k); pai[j] = __shfl(ai[j], base + k);
      pbr[j] = __shfl(br[j], base + k); pbi[j] = __shfl(bi[j], base + k);
    }
    if (r != k) {
      float fre = ar[k], fim = ai[k];
      #pragma unroll
      for (int j = 0; j < 8; ++j) {
        ar[j] -= fre * par[j] - fim * pai[j];
        ai[j] -= fre * pai[j] + fim * par[j];
        br[j] -= fre * pbr[j] - fim * pbi[j];
        bi[j] -= fre * pbi[j] + fim * pbr[j];
      }
    }
  }

  float gv[8];
  #pragma unroll
  for (int d = 0; d < 8; ++d) gv[d] = g[n * 8 + d];
  float gm = gv[0];
  #pragma unroll
  for (int d = 1; d < 8; ++d) gm = fmaxf(gm, gv[d]);
  float u[8], usum = 0.f;
  #pragma unroll
  for (int d = 0; d < 8; ++d) { u[d] = expf(gv[d] - gm); usum += u[d]; }
  float uinv = 1.f / usum;
  #pragma unroll
  for (int d = 0; d < 8; ++d) u[d] *= uinv;

  float avr = 0.f, avi = 0.f;
  #pragma unroll
  for (int d = 0; d < 8; ++d) { avr += rsr[d] * u[d]; avi += rsi[d] * u[d]; }

  float wnr = 0.f, wni = 0.f;
  #pragma unroll
  for (int d = 0; d < 8; ++d) {
    float adr = __shfl(avr, base + d), adi = __shfl(avi, base + d);
    wnr += br[d] * adr - bi[d] * adi;
    wni += br[d] * adi + bi[d] * adr;
  }

  float trr = 0.f, tri = 0.f;
  #pragma unroll
  for (int d = 0; d < 8; ++d) {
    trr += br[d] * rsr[d] + bi[d] * rsi[d];
    tri += bi[d] * rsr[d] - br[d] * rsi[d];
  }
  #pragma unroll
  for (int s = 1; s < 8; s <<= 1) { trr += __shfl_xor(trr, s); tri += __shfl_xor(tri, s); }
  trr += EPSF;

  float den = trr * trr + tri * tri;
  float wre = (wnr * trr + wni * tri) / den;
  float wim = (wni * trr - wnr * tri) / den;
  ((float2*)wc)[(size_t)item * 8 + r] = make_float2(wre, -wim);  // conj(w)
}

// beam[n,f,t] = sum_c conj(w) x ; 8f x 128t tile, float4 loads, LDS transpose to (N,T,F,2)
__global__ __launch_bounds__(256) void beamform_kernel(
    const float* __restrict__ xr, const float* __restrict__ xi,
    const float* __restrict__ wc, float* __restrict__ out) {
  __shared__ float lds[128][17];
  int n = blockIdx.z;
  int fb = blockIdx.x * 8;
  int tb = blockIdx.y * 128;
  int tid = threadIdx.x;
  int q  = tid & 31;         // t-quad within tile
  int fi = tid >> 5;         // 0..7
  int f = fb + fi;
  int t = tb + q * 4;

  float4 br = make_float4(0.f, 0.f, 0.f, 0.f);
  float4 bi = make_float4(0.f, 0.f, 0.f, 0.f);
  if (f < F_ && t < T_) {    // T divisible by 4 -> whole quad valid
    size_t e4 = ((((size_t)(n * C_) * F_ + f) * T_) + t) >> 2;
    const float2* wrow = (const float2*)wc + ((size_t)n * F_ + f) * 8;
    #pragma unroll
    for (int c = 0; c < 8; ++c) {
      float4 a = ((const float4*)xr)[e4 + (size_t)c * CS4];
      float4 b = ((const float4*)xi)[e4 + (size_t)c * CS4];
      float2 w = wrow[c];
      br.x += w.x * a.x - w.y * b.x;  bi.x += w.x * b.x + w.y * a.x;
      br.y += w.x * a.y - w.y * b.y;  bi.y += w.x * b.y + w.y * a.y;
      br.z += w.x * a.z - w.y * b.z;  bi.z += w.x * b.z + w.y * a.z;
      br.w += w.x * a.w - w.y * b.w;  bi.w += w.x * b.w + w.y * a.w;
    }
  }
  int row = q * 4, col = fi * 2;
  lds[row + 0][col] = br.x; lds[row + 0][col + 1] = bi.x;
  lds[row + 1][col] = br.y; lds[row + 1][col + 1] = bi.y;
  lds[row + 2][col] = br.z; lds[row + 2][col + 1] = bi.z;
  lds[row + 3][col] = br.w; lds[row + 3][col + 1] = bi.w;
  __syncthreads();

  int col2 = tid & 15, r0 = tid >> 4;
  #pragma unroll
  for (int pass = 0; pass < 8; ++pass) {
    int rr = pass * 16 + r0;
    int tt = tb + rr;
    int ff = fb + (col2 >> 1);
    if (tt < T_ && ff < F_)
      out[(((size_t)n * T_ + tt) * F_ + ff) * 2 + (col2 & 1)] = lds[rr][col2];
  }
}

extern "C" void kernel_launch(void* const* d_in, const int* in_sizes, int n_in,
                              void* d_out, int out_size, void* d_ws, size_t ws_size,
                              hipStream_t stream) {
  const float* m  = (const float*)d_in[0];
  const float* xr = (const float*)d_in[1];
  const float* xi = (const float*)d_in[2];
  const float* pw = (const float*)d_in[3];
  const float* pb = (const float*)d_in[4];
  const float* gw = (const float*)d_in[5];
  const float* gb = (const float*)d_in[6];
  float* ws  = (float*)d_ws;
  float* out = (float*)d_out;

  float* maxabs = ws + OFF_MAX;
  float* summ   = ws + OFF_SUM;
  float* mt     = ws + OFF_MT;
  float* Rs     = ws + OFF_RS;
  float* Rn     = ws + OFF_RN;
  float* feat   = ws + OFF_FEAT;
  float* g      = ws + OFF_G;
  float* wc     = ws + OFF_WC;

  hipMemsetAsync(maxabs, 0, 4112 * sizeof(float), stream);  // maxabs + summ contiguous
  hipLaunchKernelGGL(mask_prep, dim3(9, 47, 8), dim3(32, 8), 0, stream, m, mt, maxabs, summ);
  hipLaunchKernelGGL(covar_kernel, dim3(NF), dim3(64), 0, stream, xr, xi, mt, maxabs, summ, Rs, Rn, feat);
  hipLaunchKernelGGL(proj_kernel, dim3(64), dim3(256), 0, stream, feat, pw, pb, gw, gb, g);
  hipLaunchKernelGGL(mvdr_kernel, dim3(NF / 8), dim3(64), 0, stream, Rs, Rn, g, wc);
  hipLaunchKernelGGL(beamform_kernel, dim3(33, 12, 8), dim3(256), 0, stream, xr, xi, wc, out);
}